// Round 5
// baseline (129.477 us; speedup 1.0000x reference)
//
#include <hip/hip_runtime.h>
#include <hip/hip_bf16.h>

// DeformConv2d: x[4,4,256,36,36] f32, filter[1024,256,3,3] f32, offset[16,2] f32
// out[4,1024,36,36] f32.
// R5 restructure: eliminate the 95MB xt im2col round-trip.
//   pass 1: cvt_filter  -> wbf [1024][k'=n*256+c] bf16
//   pass 2: rowlerp     -> xrow[b][y][i][col 0..37][c 0..255] bf16 (33.6MB, row-lerped)
//   pass 3: gemm        -> B-tile generated IN-KERNEL from xrow (column-lerp, VALU)
//                          + A via global_load_lds; 128x64 tile, BK=64 (one tap, 64 ch),
//                          2-phase dbuf, XOR-swizzled LDS, XCD-grouped per b.
// ws: xrow 16,809,984 el + wbf 2,359,296 el (bf16) = 38,338,560 B.

#define HH 36
#define WW 36
#define CT 256
#define NB 16
#define KK 2304      // 9*256
#define NP 1296      // 36*36
#define OCH 1024
#define OUTG 256
#define XRPITCH (38 * 256)          // per (b,y,i) row: 38 cols x 256 ch

typedef __attribute__((ext_vector_type(8))) short short8;
typedef __attribute__((ext_vector_type(8))) unsigned short us8;
typedef __attribute__((ext_vector_type(4))) float f32x4;
typedef __attribute__((ext_vector_type(4))) unsigned short us4;

__device__ __forceinline__ unsigned short f2bf(float v) {
    unsigned u = __float_as_uint(v);
    u += 0x7fffu + ((u >> 16) & 1u);   // RNE
    return (unsigned short)(u >> 16);
}
__device__ __forceinline__ float bfu2f(unsigned short u) {
    return __uint_as_float((unsigned)u << 16);
}

// ---------------- kernel 1: filter fp32 [o][c*9+n] -> bf16 [o][n*256+c] ----------
__global__ __launch_bounds__(256) void cvt_filter(const float* __restrict__ f,
                                                  unsigned short* __restrict__ w) {
    const int o = blockIdx.x;
    const float* fo = f + (size_t)o * KK;
    unsigned short* wo = w + (size_t)o * KK;
    for (int k4 = threadIdx.x * 4; k4 < KK; k4 += 1024) {
        int n = k4 >> 8;
        int c = k4 & 255;
        us4 v;
#pragma unroll
        for (int cc = 0; cc < 4; ++cc) v[cc] = f2bf(fo[(c + cc) * 9 + n]);
        *reinterpret_cast<us4*>(wo + k4) = v;
    }
}

// ---------------- kernel 2: row-lerp pre-pass -> xrow[b][y][i][col][c] bf16 -------
// grid 4608 = 16b * 36y * 8cg(32c), XCD-swizzled (2 b per XCD, matches gemm).
__global__ __launch_bounds__(256) void rowlerp_kernel(const float* __restrict__ x,
                                                      const float* __restrict__ off,
                                                      unsigned short* __restrict__ xrow) {
    const int wid = (blockIdx.x & 7) * 576 + (blockIdx.x >> 3);
    const int b = wid / 288;
    const int rem = wid - b * 288;
    const int y = rem >> 3;
    const int cg = rem & 7;
    const int c0 = cg * 32;
    const int tid = threadIdx.x;
    const float sx = 3.0f / off[2 * b + 0];

    float gl[3], gr[3]; int qrow[6]; bool qok[6];
#pragma unroll
    for (int i = 0; i < 3; ++i) {
        float px = (float)(y + 1) + (float)(i - 1) * sx;
        float pc = fminf(fmaxf(px, 0.f), 37.f);
        float fl = floorf(px);
        float ql = fminf(fmaxf(fl, 0.f), 37.f);
        float qr = fminf(fmaxf(fl + 1.f, 0.f), 37.f);
        gl[i] = 1.f + (ql - pc);
        gr[i] = 1.f - (qr - pc);
        qrow[i * 2]     = (int)ql; qok[i * 2]     = (ql >= 1.f && ql <= 36.f);
        qrow[i * 2 + 1] = (int)qr; qok[i * 2 + 1] = (qr >= 1.f && qr <= 36.f);
    }

    // LDS transpose tile: xin[slot 6][c 32][col 36] pitch 37
    __shared__ float xin[6 * 32 * 37];
    const float* xb = x + (size_t)(b * CT + c0) * NP;
#pragma unroll
    for (int s = 0; s < 6; ++s) {
        const bool ok = qok[s];
        const float* src = xb + (qrow[s] - 1) * WW;
        for (int e = tid; e < 32 * 36; e += 256) {
            int c = e / 36, col = e - c * 36;
            xin[(s * 32 + c) * 37 + col] = ok ? src[c * NP + col] : 0.f;
        }
    }
    __syncthreads();

    // compute + store: tasks (i, col38, c-pair16); dword (bf16x2) stores, 64B/16 lanes
    unsigned short* orow = xrow + (((size_t)b * HH + y) * 3) * XRPITCH + c0;
    for (int t = tid; t < 3 * 38 * 16; t += 256) {
        const int c16 = t & 15;
        const int col = (t >> 4) % 38;
        const int i = t / (16 * 38);
        unsigned outw = 0;
        if (col >= 1 && col <= 36) {
            const float* a = &xin[((i * 2) * 32 + c16 * 2) * 37 + col - 1];
            const float* bq = &xin[((i * 2 + 1) * 32 + c16 * 2) * 37 + col - 1];
            float v0 = gl[i] * a[0]  + gr[i] * bq[0];
            float v1 = gl[i] * a[37] + gr[i] * bq[37];
            outw = (unsigned)f2bf(v0) | ((unsigned)f2bf(v1) << 16);
        }
        *reinterpret_cast<unsigned*>(orow + (size_t)i * XRPITCH + col * 256 + c16 * 2) = outw;
    }
}

// ---------------- kernel 3: MFMA GEMM with in-kernel column-lerp B-gen ------------
__global__ __launch_bounds__(256) void gemm_kernel(const unsigned short* __restrict__ wbf,
                                                   const unsigned short* __restrict__ xrow,
                                                   const float* __restrict__ off,
                                                   float* __restrict__ out) {
    // 672 blocks = 8 XCD * 84; per XCD 2 b's (42 tiles/b) -> xrow[b] L2-resident
    const int wid = (blockIdx.x & 7) * 84 + (blockIdx.x >> 3);
    const int b = wid / 42;
    const int rem = wid - b * 42;
    const int mt = rem / 21;
    const int nt = rem - mt * 21;
    const int m0 = mt * 128;
    const int p0 = nt * 64;
    const int g = b & 3;
    const int mimg = b >> 2;

    const unsigned short* Ab = wbf + (size_t)(g * OUTG + m0) * KK;

    __shared__ __align__(16) unsigned short As[2][128 * 64];
    __shared__ __align__(16) unsigned short Bs[2][64 * 64];

    const int tid = threadIdx.x;
    const int wave = tid >> 6, lane = tid & 63;
    const int wr = wave >> 1, wc = wave & 1;
    const int l8 = lane >> 3;
    const int sgrp = (lane & 7) ^ l8;         // pre-swizzled A source column group

    // ---- per-thread B-gen setup: this thread owns p = p0 + lane for all kt ----
    const int pclamp = min(p0 + lane, NP - 1);
    const int py_ = pclamp / 36;
    const int px_ = pclamp - py_ * 36;
    const float sy = 3.0f / off[2 * b + 1];
    int qoffL[3], qoffR[3]; float gyl[3], gyr[3];
#pragma unroll
    for (int j = 0; j < 3; ++j) {
        float py = (float)(px_ + 1) + (float)(j - 1) * sy;
        float pc = fminf(fmaxf(py, 0.f), 37.f);
        float fl = floorf(py);
        float ql = fminf(fmaxf(fl, 0.f), 37.f);
        float qr = fminf(fmaxf(fl + 1.f, 0.f), 37.f);
        gyl[j] = 1.f + (ql - pc);
        gyr[j] = 1.f - (qr - pc);
        qoffL[j] = (int)ql * 256;
        qoffR[j] = (int)qr * 256;
    }
    // base for (b, y): xrow + ((b*36+y)*3 + i)*XRPITCH
    const unsigned short* XRB = xrow + (((size_t)b * HH + py_) * 3) * XRPITCH;
    const int oct0 = wave * 2;                    // this wave's two c-octets
    // swizzled LDS byte targets (key = p&7 = lane&7)
    unsigned short* bs0[2]; unsigned short* bs1[2];
#pragma unroll
    for (int u = 0; u < 2; ++u) {
        bs0[u] = &Bs[u][lane * 64 + ((oct0)     ^ (lane & 7)) * 8];
        bs1[u] = &Bs[u][lane * 64 + ((oct0 + 1) ^ (lane & 7)) * 8];
    }

    f32x4 acc[4][2] = {};
    us8 L0, R0, L1, R1;

#define STAGE_A(BUF, KT) do {                                                     \
    const int k0_ = (KT) * 64;                                                    \
    _Pragma("unroll")                                                             \
    for (int ii = 0; ii < 4; ++ii) {                                              \
        const int inst = wave * 4 + ii;                                           \
        const int row = inst * 8 + l8;                                            \
        const unsigned short* srcA = Ab + (size_t)row * KK + k0_ + sgrp * 8;      \
        __builtin_amdgcn_global_load_lds(                                         \
            (const __attribute__((address_space(1))) void*)srcA,                  \
            (__attribute__((address_space(3))) void*)&As[BUF][inst * 512], 16, 0, 0); \
    }                                                                             \
} while (0)

#define BLOAD(KT) do {                                                            \
    const int n_ = (KT) >> 2;                                                     \
    const int i_ = (n_ >= 6) ? 2 : (n_ >= 3 ? 1 : 0);                             \
    const int j_ = n_ - i_ * 3;                                                   \
    const unsigned short* rowb = XRB + i_ * XRPITCH + ((KT) & 3) * 64 + oct0 * 8; \
    L0 = *reinterpret_cast<const us8*>(rowb + qoffL[j_]);                         \
    R0 = *reinterpret_cast<const us8*>(rowb + qoffR[j_]);                         \
    L1 = *reinterpret_cast<const us8*>(rowb + qoffL[j_] + 8);                     \
    R1 = *reinterpret_cast<const us8*>(rowb + qoffR[j_] + 8);                     \
    wgl = gyl[j_]; wgr = gyr[j_];                                                 \
} while (0)

#define BWRITE(BUF) do {                                                          \
    us8 o0, o1;                                                                   \
    _Pragma("unroll")                                                             \
    for (int e = 0; e < 8; ++e) {                                                 \
        o0[e] = f2bf(wgl * bfu2f(L0[e]) + wgr * bfu2f(R0[e]));                    \
        o1[e] = f2bf(wgl * bfu2f(L1[e]) + wgr * bfu2f(R1[e]));                    \
    }                                                                             \
    *reinterpret_cast<us8*>(bs0[BUF]) = o0;                                       \
    *reinterpret_cast<us8*>(bs1[BUF]) = o1;                                       \
} while (0)

#define COMPUTE(BUF) do {                                                         \
    _Pragma("unroll")                                                             \
    for (int kk = 0; kk < 2; ++kk) {                                              \
        short8 a[4], bfr[2];                                                      \
        const int g8 = (((kk * 4) + (lane >> 4)) ^ (lane & 7)) << 3;              \
        const int rA = wr * 64 + (lane & 15);                                     \
        const int rB = wc * 32 + (lane & 15);                                     \
        _Pragma("unroll")                                                         \
        for (int m = 0; m < 4; ++m)                                               \
            a[m] = *(const short8*)&As[BUF][(rA + m * 16) * 64 + g8];             \
        _Pragma("unroll")                                                         \
        for (int n = 0; n < 2; ++n)                                               \
            bfr[n] = *(const short8*)&Bs[BUF][(rB + n * 16) * 64 + g8];           \
        _Pragma("unroll")                                                         \
        for (int m = 0; m < 4; ++m)                                               \
            _Pragma("unroll")                                                     \
            for (int n = 0; n < 2; ++n)                                           \
                acc[m][n] = __builtin_amdgcn_mfma_f32_16x16x32_bf16(              \
                    a[m], bfr[n], acc[m][n], 0, 0, 0);                            \
    }                                                                             \
} while (0)

    float wgl, wgr;
    STAGE_A(0, 0);
    BLOAD(0);
    BWRITE(0);
    __syncthreads();

    int cur = 0;
#pragma unroll 1
    for (int kt = 0; kt < 35; ++kt) {
        STAGE_A(cur ^ 1, kt + 1);     // A loads fly under MFMA
        BLOAD(kt + 1);                // B source loads fly under MFMA
        COMPUTE(cur);
        BWRITE(cur ^ 1);              // lerp+pack+ds_write after compute
        __syncthreads();              // drains vmcnt + lgkmcnt: next tile ready
        cur ^= 1;
    }
    COMPUTE(cur);

#undef STAGE_A
#undef BLOAD
#undef BWRITE
#undef COMPUTE

    float* ob = out + ((size_t)mimg * OCH + g * OUTG) * NP;
    const int o0 = m0 + wr * 64 + ((lane >> 4) << 2);
    const int pc = p0 + wc * 32 + (lane & 15);
#pragma unroll
    for (int n = 0; n < 2; ++n) {
        int p = pc + n * 16;
        if (p >= NP) continue;
#pragma unroll
        for (int m = 0; m < 4; ++m) {
#pragma unroll
            for (int r = 0; r < 4; ++r)
                ob[(size_t)(o0 + m * 16 + r) * NP + p] = acc[m][n][r];
        }
    }
}

extern "C" void kernel_launch(void* const* d_in, const int* in_sizes, int n_in,
                              void* d_out, int out_size, void* d_ws, size_t ws_size,
                              hipStream_t stream) {
    const float* x   = (const float*)d_in[0];
    const float* tf  = (const float*)d_in[1];
    const float* off = (const float*)d_in[2];
    float* out = (float*)d_out;

    unsigned short* xrow = (unsigned short*)d_ws;                   // [16][36][3][38][256] bf16
    unsigned short* wbf  = xrow + (size_t)NB * HH * 3 * XRPITCH;    // [1024][2304] bf16

    hipLaunchKernelGGL(cvt_filter, dim3(OCH), dim3(256), 0, stream, tf, wbf);
    hipLaunchKernelGGL(rowlerp_kernel, dim3(NB * HH * 8), dim3(256), 0, stream, x, off, xrow);
    hipLaunchKernelGGL(gemm_kernel, dim3(672), dim3(256), 0, stream, wbf, xrow, off, out);
}

// Round 6
// 114.790 us; speedup vs baseline: 1.1279x; 1.1279x over previous
//
#include <hip/hip_runtime.h>
#include <hip/hip_bf16.h>

// DeformConv2d: x[4,4,256,36,36] f32, filter[1024,256,3,3] f32, offset[16,2] f32
// out[4,1024,36,36] f32.
// R6: no im2col round-trip. K-order k = ((i*4+cc)*3+j)*64+cl (group g=(i,cc) outer,
// tap-col j inner) so one staged Xs slice [3y][40col][64c] serves 3 K-steps.
//   pass 1: cvt_filter -> wbf[1024][k] bf16 (permuted to K-order)
//   pass 2: rowlerp    -> xrow[b][y][i][col38][c256] bf16 (row-lerped, 33.6MB)
//   pass 3: gemm 128x64: A via global_load_lds; Xs staged via global_load_lds
//           (coalesced, swizzled source); B-tile = column-lerp from Xs in LDS
//           (ds_read_b128 + VALU + ds_write_b128); 3-deep pipeline, 1 barrier/iter.
// ws: xrow 16,809,984 el + wbf 2,359,296 el (bf16) = 38,338,560 B.

#define HH 36
#define WW 36
#define CT 256
#define NB 16
#define KK 2304      // 36 q-steps * 64
#define NP 1296      // 36*36
#define OCH 1024
#define OUTG 256
#define XRPITCH (38 * 256)          // per (b,y,i): 38 cols x 256 ch

typedef __attribute__((ext_vector_type(8))) short short8;
typedef __attribute__((ext_vector_type(8))) unsigned short us8;
typedef __attribute__((ext_vector_type(4))) float f32x4;
typedef __attribute__((ext_vector_type(4))) unsigned short us4;

__device__ __forceinline__ unsigned short f2bf(float v) {
    unsigned u = __float_as_uint(v);
    u += 0x7fffu + ((u >> 16) & 1u);   // RNE
    return (unsigned short)(u >> 16);
}
__device__ __forceinline__ float bfu2f(unsigned short u) {
    return __uint_as_float((unsigned)u << 16);
}

// ---------------- kernel 1: filter fp32 [o][c*9+n] -> bf16 K-order ----------------
__global__ __launch_bounds__(256) void cvt_filter(const float* __restrict__ f,
                                                  unsigned short* __restrict__ w) {
    const int o = blockIdx.x;
    const float* fo = f + (size_t)o * KK;
    unsigned short* wo = w + (size_t)o * KK;
    for (int k4 = threadIdx.x * 4; k4 < KK; k4 += 1024) {
        const int q = k4 >> 6;           // 0..35
        const int cl = k4 & 63;
        const int j = q % 3;
        const int gq = q / 3;            // (i,cc)
        const int cc = gq & 3, i = gq >> 2;
        const int cbase = cc * 64 + cl;
        us4 v;
#pragma unroll
        for (int e = 0; e < 4; ++e) v[e] = f2bf(fo[(cbase + e) * 9 + i * 3 + j]);
        *reinterpret_cast<us4*>(wo + k4) = v;
    }
}

// ---------------- kernel 2: row-lerp pre-pass -> xrow[b][y][i][col][c] bf16 -------
__global__ __launch_bounds__(256) void rowlerp_kernel(const float* __restrict__ x,
                                                      const float* __restrict__ off,
                                                      unsigned short* __restrict__ xrow) {
    const int wid = (blockIdx.x & 7) * 576 + (blockIdx.x >> 3);
    const int b = wid / 288;
    const int rem = wid - b * 288;
    const int y = rem >> 3;
    const int cg = rem & 7;
    const int c0 = cg * 32;
    const int tid = threadIdx.x;
    const float sx = 3.0f / off[2 * b + 0];

    float gl[3], gr[3]; int qrow[6]; bool qok[6];
#pragma unroll
    for (int i = 0; i < 3; ++i) {
        float px = (float)(y + 1) + (float)(i - 1) * sx;
        float pc = fminf(fmaxf(px, 0.f), 37.f);
        float fl = floorf(px);
        float ql = fminf(fmaxf(fl, 0.f), 37.f);
        float qr = fminf(fmaxf(fl + 1.f, 0.f), 37.f);
        gl[i] = 1.f + (ql - pc);
        gr[i] = 1.f - (qr - pc);
        qrow[i * 2]     = (int)ql; qok[i * 2]     = (ql >= 1.f && ql <= 36.f);
        qrow[i * 2 + 1] = (int)qr; qok[i * 2 + 1] = (qr >= 1.f && qr <= 36.f);
    }

    __shared__ float xin[6 * 32 * 37];
    const float* xb = x + (size_t)(b * CT + c0) * NP;
#pragma unroll
    for (int s = 0; s < 6; ++s) {
        const bool ok = qok[s];
        const float* src = xb + (qrow[s] - 1) * WW;
        for (int e = tid; e < 32 * 36; e += 256) {
            int c = e / 36, col = e - c * 36;
            xin[(s * 32 + c) * 37 + col] = ok ? src[c * NP + col] : 0.f;
        }
    }
    __syncthreads();

    unsigned short* orow = xrow + (((size_t)b * HH + y) * 3) * XRPITCH + c0;
    for (int t = tid; t < 3 * 38 * 16; t += 256) {
        const int c16 = t & 15;
        const int col = (t >> 4) % 38;
        const int i = t / (16 * 38);
        unsigned outw = 0;
        if (col >= 1 && col <= 36) {
            const float* a = &xin[((i * 2) * 32 + c16 * 2) * 37 + col - 1];
            const float* bq = &xin[((i * 2 + 1) * 32 + c16 * 2) * 37 + col - 1];
            float v0 = gl[i] * a[0]  + gr[i] * bq[0];
            float v1 = gl[i] * a[37] + gr[i] * bq[37];
            outw = (unsigned)f2bf(v0) | ((unsigned)f2bf(v1) << 16);
        }
        *reinterpret_cast<unsigned*>(orow + (size_t)i * XRPITCH + col * 256 + c16 * 2) = outw;
    }
}

// ---------------- kernel 3: MFMA GEMM, B generated from staged Xs -----------------
__global__ __launch_bounds__(256) void gemm_kernel(const unsigned short* __restrict__ wbf,
                                                   const unsigned short* __restrict__ xrow,
                                                   const float* __restrict__ off,
                                                   float* __restrict__ out) {
    const int wid = (blockIdx.x & 7) * 84 + (blockIdx.x >> 3);   // 672 = 8 XCD * 84
    const int b = wid / 42;
    const int rem = wid - b * 42;
    const int mt = rem / 21;
    const int nt = rem - mt * 21;
    const int m0 = mt * 128;
    const int p0 = nt * 64;
    const int g = b & 3;
    const int mimg = b >> 2;

    const unsigned short* Ab = wbf + (size_t)(g * OUTG + m0) * KK;

    __shared__ __align__(16) unsigned short As[2][128 * 64];   // 32 KB
    __shared__ __align__(16) unsigned short Bs[2][64 * 64];    // 16 KB
    __shared__ __align__(16) unsigned short Xs[2][3 * 40 * 64];// 30 KB

    const int tid = threadIdx.x;
    const int wave = tid >> 6, lane = tid & 63;
    const int wr = wave >> 1, wc = wave & 1;
    const int l8 = lane >> 3;
    const int sgrp = (lane & 7) ^ l8;                 // swizzled source col-group
    const int y0 = p0 / 36;

    // per-thread B-gen params for p = p0 + lane
    const int pclamp = min(p0 + lane, NP - 1);
    const int py_ = pclamp / 36;
    const int px_ = pclamp - py_ * 36;
    const int yloc = py_ - y0;                        // 0..2
    const float sy = 3.0f / off[2 * b + 1];
    int qL[3], qR[3]; float gyl[3], gyr[3];
#pragma unroll
    for (int j = 0; j < 3; ++j) {
        float py = (float)(px_ + 1) + (float)(j - 1) * sy;
        float pc = fminf(fmaxf(py, 0.f), 37.f);
        float fl = floorf(py);
        float ql = fminf(fmaxf(fl, 0.f), 37.f);
        float qr = fminf(fmaxf(fl + 1.f, 0.f), 37.f);
        gyl[j] = 1.f + (ql - pc);
        gyr[j] = 1.f - (qr - pc);
        qL[j] = (int)ql;
        qR[j] = (int)qr;
    }
    const int oct0 = wave * 2;

    f32x4 acc[4][2] = {};

#define STAGE_A(BUF, Q) do {                                                      \
    const int k0_ = (Q) * 64;                                                     \
    _Pragma("unroll")                                                             \
    for (int ii = 0; ii < 4; ++ii) {                                              \
        const int inst = wave * 4 + ii;                                           \
        const int row = inst * 8 + l8;                                            \
        const unsigned short* srcA = Ab + (size_t)row * KK + k0_ + sgrp * 8;      \
        __builtin_amdgcn_global_load_lds(                                         \
            (const __attribute__((address_space(1))) void*)srcA,                  \
            (__attribute__((address_space(3))) void*)&As[BUF][inst * 512], 16, 0, 0); \
    }                                                                             \
} while (0)

// stage Xs[3y][40col][64c] for group G=(i,cc): 15 segs of 8 cols x 128B, swizzled src
#define STAGE_X(BUF, G) do {                                                      \
    const int i_ = (G) >> 2, cc_ = (G) & 3;                                       \
    _Pragma("unroll")                                                             \
    for (int ii = 0; ii < 4; ++ii) {                                              \
        const int s = ii * 4 + wave;                                              \
        if (s < 15) {                                                             \
            const int yy = min(y0 + s / 5, 35);                                   \
            const int col = min((s % 5) * 8 + l8, 37);                            \
            const unsigned short* srcX = xrow                                     \
                + (((size_t)b * HH + yy) * 3 + i_) * XRPITCH                      \
                + col * 256 + cc_ * 64 + sgrp * 8;                                \
            __builtin_amdgcn_global_load_lds(                                     \
                (const __attribute__((address_space(1))) void*)srcX,              \
                (__attribute__((address_space(3))) void*)&Xs[BUF][s * 512], 16, 0, 0); \
        }                                                                         \
    }                                                                             \
} while (0)

// generate this thread's 16 B-elements for q (tap j) from Xs, write to Bs
#define BGEN(BBUF, XBUF, J) do {                                                  \
    const int qc_l = qL[J], qc_r = qR[J];                                         \
    const float wgl = gyl[J], wgr = gyr[J];                                       \
    const int rl = (yloc * 40 + qc_l) * 64, rr = (yloc * 40 + qc_r) * 64;         \
    _Pragma("unroll")                                                             \
    for (int u = 0; u < 2; ++u) {                                                 \
        const int oct = oct0 + u;                                                 \
        us8 L = *(const us8*)&Xs[XBUF][rl + ((oct ^ (qc_l & 7)) * 8)];            \
        us8 R = *(const us8*)&Xs[XBUF][rr + ((oct ^ (qc_r & 7)) * 8)];            \
        us8 o;                                                                    \
        _Pragma("unroll")                                                         \
        for (int e = 0; e < 8; ++e)                                               \
            o[e] = f2bf(wgl * bfu2f(L[e]) + wgr * bfu2f(R[e]));                   \
        *(us8*)&Bs[BBUF][lane * 64 + ((oct ^ (lane & 7)) * 8)] = o;               \
    }                                                                             \
} while (0)

#define COMPUTE(BUF) do {                                                         \
    _Pragma("unroll")                                                             \
    for (int kk = 0; kk < 2; ++kk) {                                              \
        short8 a[4], bfr[2];                                                      \
        const int g8 = (((kk * 4) + (lane >> 4)) ^ (lane & 7)) << 3;              \
        const int rA = wr * 64 + (lane & 15);                                     \
        const int rB = wc * 32 + (lane & 15);                                     \
        _Pragma("unroll")                                                         \
        for (int m = 0; m < 4; ++m)                                               \
            a[m] = *(const short8*)&As[BUF][(rA + m * 16) * 64 + g8];             \
        _Pragma("unroll")                                                         \
        for (int n = 0; n < 2; ++n)                                               \
            bfr[n] = *(const short8*)&Bs[BUF][(rB + n * 16) * 64 + g8];           \
        _Pragma("unroll")                                                         \
        for (int m = 0; m < 4; ++m)                                               \
            _Pragma("unroll")                                                     \
            for (int n = 0; n < 2; ++n)                                           \
                acc[m][n] = __builtin_amdgcn_mfma_f32_16x16x32_bf16(              \
                    a[m], bfr[n], acc[m][n], 0, 0, 0);                            \
    }                                                                             \
} while (0)

// one pipeline iteration: prepare q (stage A, optional stage X, gen B), compute q-1
#define ITER(Q, J, DOSTAGE, GN) do {                                              \
    if (DOSTAGE) STAGE_X((GN) & 1, (GN));                                         \
    STAGE_A((Q) & 1, (Q));                                                        \
    BGEN((Q) & 1, ((Q) / 3) & 1, J);                                              \
    COMPUTE(((Q) - 1) & 1);                                                       \
    __syncthreads();                                                              \
} while (0)

    // prologue: stage group 0 + A(0); gen B(0)
    STAGE_X(0, 0);
    STAGE_A(0, 0);
    __syncthreads();
    BGEN(0, 0, 0);
    __syncthreads();

#pragma unroll 1
    for (int G = 0; G < 11; ++G) {
        const int qb = G * 3;
        ITER(qb + 1, 1, false, 0);
        ITER(qb + 2, 2, true, G + 1);
        ITER(qb + 3, 0, false, 0);
    }
    ITER(34, 1, false, 0);
    ITER(35, 2, false, 0);
    COMPUTE(1);                      // q = 35

#undef STAGE_A
#undef STAGE_X
#undef BGEN
#undef COMPUTE
#undef ITER

    float* ob = out + ((size_t)mimg * OCH + g * OUTG) * NP;
    const int o0 = m0 + wr * 64 + ((lane >> 4) << 2);
    const int pc = p0 + wc * 32 + (lane & 15);
#pragma unroll
    for (int n = 0; n < 2; ++n) {
        int p = pc + n * 16;
        if (p >= NP) continue;
#pragma unroll
        for (int m = 0; m < 4; ++m) {
#pragma unroll
            for (int r = 0; r < 4; ++r)
                ob[(size_t)(o0 + m * 16 + r) * NP + p] = acc[m][n][r];
        }
    }
}

extern "C" void kernel_launch(void* const* d_in, const int* in_sizes, int n_in,
                              void* d_out, int out_size, void* d_ws, size_t ws_size,
                              hipStream_t stream) {
    const float* x   = (const float*)d_in[0];
    const float* tf  = (const float*)d_in[1];
    const float* off = (const float*)d_in[2];
    float* out = (float*)d_out;

    unsigned short* xrow = (unsigned short*)d_ws;                   // [16][36][3][38][256] bf16
    unsigned short* wbf  = xrow + (size_t)NB * HH * 3 * XRPITCH;    // [1024][2304] bf16

    hipLaunchKernelGGL(cvt_filter, dim3(OCH), dim3(256), 0, stream, tf, wbf);
    hipLaunchKernelGGL(rowlerp_kernel, dim3(NB * HH * 8), dim3(256), 0, stream, x, off, xrow);
    hipLaunchKernelGGL(gemm_kernel, dim3(672), dim3(256), 0, stream, wbf, xrow, off, out);
}

// Round 7
// 73.907 us; speedup vs baseline: 1.7519x; 1.5532x over previous
//
#include <hip/hip_runtime.h>
#include <hip/hip_bf16.h>

// DeformConv2d: x[4,4,256,36,36] f32, filter[1024,256,3,3] f32, offset[16,2] f32
// out[4,1024,36,36] f32.
// R7 = R3 structure (best: xt im2col + 2-phase dbuf MFMA gemm) with a rebuilt
// sample kernel: LDS xr[3i][38col][64c] f32 (c-contiguous) -> phase-2 column-lerp
// uses ds_read_b128 + v_cvt_pk_bf16_f32 + uint4 stores. K layout k' = n*256+c.
// ws: xt [16][1296][2304] bf16 + w' [1024][2304] bf16 = 100,270,080 B.

#define HH 36
#define WW 36
#define CT 256
#define NB 16
#define KK 2304      // 9*256
#define NP 1296      // 36*36
#define OCH 1024
#define OUTG 256

typedef __attribute__((ext_vector_type(8))) short short8;
typedef __attribute__((ext_vector_type(4))) float f32x4;
typedef __attribute__((ext_vector_type(4))) unsigned short us4;
typedef __attribute__((ext_vector_type(4))) unsigned uint4v;

__device__ __forceinline__ unsigned short f2bf(float v) {
    unsigned u = __float_as_uint(v);
    u += 0x7fffu + ((u >> 16) & 1u);   // RNE
    return (unsigned short)(u >> 16);
}
__device__ __forceinline__ unsigned pk2bf(float lo, float hi) {
    __hip_bfloat162 h = __float22bfloat162_rn(float2{lo, hi});   // v_cvt_pk_bf16_f32
    return *reinterpret_cast<unsigned*>(&h);
}

// ---------------- kernel 1: filter fp32 [o][c*9+n] -> bf16 [o][n*256+c] ----------
__global__ __launch_bounds__(256) void cvt_filter(const float* __restrict__ f,
                                                  unsigned short* __restrict__ w) {
    const int o = blockIdx.x;
    const float* fo = f + (size_t)o * KK;
    unsigned short* wo = w + (size_t)o * KK;
    for (int k4 = threadIdx.x * 4; k4 < KK; k4 += 1024) {
        int n = k4 >> 8;          // tap
        int c = k4 & 255;         // channel (multiple of 4)
        us4 v;
#pragma unroll
        for (int cc = 0; cc < 4; ++cc) v[cc] = f2bf(fo[(c + cc) * 9 + n]);
        *reinterpret_cast<us4*>(wo + k4) = v;
    }
}

// ---------------- kernel 2: deformable bilinear sampling -> Xoff^T bf16 -----------
// grid 1152 = 16b * 36y * 2 half(128ch), XCD-swizzled (2 b per XCD, matches gemm).
__global__ __launch_bounds__(256) void sample_kernel(const float* __restrict__ x,
                                                     const float* __restrict__ off,
                                                     unsigned short* __restrict__ xt) {
    const int wid = (blockIdx.x & 7) * 144 + (blockIdx.x >> 3);
    const int b = wid / 72;
    const int rem = wid - b * 72;
    const int y = rem >> 1;
    const int half = rem & 1;
    const int tid = threadIdx.x;
    const float sx = 3.0f / off[2 * b + 0];
    const float sy = 3.0f / off[2 * b + 1];

    // row (i) tables: per-thread registers (block-uniform)
    int qxl[3], qxr[3]; float gxl[3], gxr[3];
    bool lok[3], rok[3];
#pragma unroll
    for (int i = 0; i < 3; ++i) {
        float px = (float)(y + 1) + (float)(i - 1) * sx;
        float pc = fminf(fmaxf(px, 0.f), 37.f);
        float fl = floorf(px);
        float ql = fminf(fmaxf(fl, 0.f), 37.f);
        float qr = fminf(fmaxf(fl + 1.f, 0.f), 37.f);
        qxl[i] = (int)ql; qxr[i] = (int)qr;
        gxl[i] = 1.f + (ql - pc);
        gxr[i] = 1.f - (qr - pc);
        lok[i] = (qxl[i] >= 1 && qxl[i] <= 36);
        rok[i] = (qxr[i] >= 1 && qxr[i] <= 36);
    }

    // column (x,j) tables in LDS
    __shared__ int   s_qyl[HH * 3], s_qyr[HH * 3];
    __shared__ float s_gyl[HH * 3], s_gyr[HH * 3];
    if (tid < HH * 3) {
        int xx = tid / 3, j = tid % 3;
        float py = (float)(xx + 1) + (float)(j - 1) * sy;
        float pc = fminf(fmaxf(py, 0.f), 37.f);
        float fl = floorf(py);
        float ql = fminf(fmaxf(fl, 0.f), 37.f);
        float qr = fminf(fmaxf(fl + 1.f, 0.f), 37.f);
        s_qyl[tid] = (int)ql; s_qyr[tid] = (int)qr;
        s_gyl[tid] = 1.f + (ql - pc);
        s_gyr[tid] = 1.f - (qr - pc);
    }

    // row-lerped tile, c-contiguous: xr[i][col 0..37][c 0..63] f32 (29.2 KB)
    __shared__ float xr[3 * 38 * 64];

    for (int chunk = 0; chunk < 2; ++chunk) {
        const int c0 = half * 128 + chunk * 64;
        __syncthreads();      // xr reusable (prev phase-2 done); covers tables iter0

        // boundary cols 0 and 37 are zero (zero padding)
        for (int t = tid; t < 384; t += 256) {
            int i = t / 128, r3 = t & 127;
            int col = (r3 & 64) ? 37 : 0, c = r3 & 63;
            xr[(i * 38 + col) * 64 + c] = 0.f;
        }

        // phase 1: row-lerp. tasks (i, c, colquad): coalesced float4 col-reads,
        // 4 scalar LDS writes (stride 256B) per task.
        const float* xb = x + (size_t)(b * CT + c0) * NP;
        for (int t = tid; t < 3 * 64 * 9; t += 256) {
            const int i = t / 576;
            const int r2 = t - i * 576;
            const int c = r2 / 9;
            const int cq = r2 - c * 9;
            const int colb = 1 + cq * 4;          // padded col of elem 0
            const float* xc = xb + c * NP;
            float4 vl = make_float4(0.f, 0.f, 0.f, 0.f);
            float4 vr = vl;
            if (lok[i]) vl = *(const float4*)(xc + (qxl[i] - 1) * WW + colb - 1);
            if (rok[i]) vr = *(const float4*)(xc + (qxr[i] - 1) * WW + colb - 1);
            float* dst = &xr[(i * 38 + colb) * 64 + c];
            dst[0]   = gxl[i] * vl.x + gxr[i] * vr.x;
            dst[64]  = gxl[i] * vl.y + gxr[i] * vr.y;
            dst[128] = gxl[i] * vl.z + gxr[i] * vr.z;
            dst[192] = gxl[i] * vl.w + gxr[i] * vr.w;
        }
        __syncthreads();

        // phase 2: column-lerp + pack. tasks (xi, c8): 9 taps x 8 channels each.
        for (int t = tid; t < 36 * 8; t += 256) {
            const int xi = t >> 3;
            const int c8 = t & 7;
            unsigned short* op = xt + ((size_t)b * NP + y * WW + xi) * KK + c0 + c8 * 8;
#pragma unroll
            for (int n = 0; n < 9; ++n) {
                const int i = n / 3, j = n - i * 3;
                const int tq = xi * 3 + j;
                const float gl = s_gyl[tq], gr = s_gyr[tq];
                const float* L = &xr[(i * 38 + s_qyl[tq]) * 64 + c8 * 8];
                const float* R = &xr[(i * 38 + s_qyr[tq]) * 64 + c8 * 8];
                f32x4 L0 = *(const f32x4*)L, L1 = *(const f32x4*)(L + 4);
                f32x4 R0 = *(const f32x4*)R, R1 = *(const f32x4*)(R + 4);
                uint4v w;
                w[0] = pk2bf(gl * L0[0] + gr * R0[0], gl * L0[1] + gr * R0[1]);
                w[1] = pk2bf(gl * L0[2] + gr * R0[2], gl * L0[3] + gr * R0[3]);
                w[2] = pk2bf(gl * L1[0] + gr * R1[0], gl * L1[1] + gr * R1[1]);
                w[3] = pk2bf(gl * L1[2] + gr * R1[2], gl * L1[3] + gr * R1[3]);
                *reinterpret_cast<uint4v*>(op + n * 256) = w;
            }
        }
    }
}

// ---------------- kernel 3: MFMA GEMM, 128x64 tile, BK=64, dbuf, swizzled ---------
__global__ __launch_bounds__(256) void gemm_kernel(const unsigned short* __restrict__ wbf,
                                                   const unsigned short* __restrict__ xt,
                                                   float* __restrict__ out) {
    // 672 blocks = 8 XCD * 84; 84 per XCD = 2 b's worth (42 tiles per b)
    const int wid = (blockIdx.x & 7) * 84 + (blockIdx.x >> 3);
    const int b = wid / 42;
    const int rem = wid - b * 42;
    const int mt = rem / 21;
    const int nt = rem - mt * 21;
    const int m0 = mt * 128;
    const int p0 = nt * 64;
    const int g = b & 3;
    const int mimg = b >> 2;

    const unsigned short* Ab = wbf + (size_t)(g * OUTG + m0) * KK;
    const unsigned short* Bb = xt + (size_t)b * NP * KK;

    __shared__ __align__(16) unsigned short As[2][128 * 64];
    __shared__ __align__(16) unsigned short Bs[2][64 * 64];

    const int tid = threadIdx.x;
    const int wave = tid >> 6, lane = tid & 63;
    const int wr = wave >> 1, wc = wave & 1;
    const int l8 = lane >> 3;
    const int sgrp = (lane & 7) ^ l8;         // pre-swizzled source column group

    f32x4 acc[4][2] = {};

#define STAGE(BUF, KT) do {                                                       \
    const int k0_ = (KT) * 64;                                                    \
    _Pragma("unroll")                                                             \
    for (int ii = 0; ii < 4; ++ii) {                                              \
        const int inst = wave * 4 + ii;                                           \
        const int row = inst * 8 + l8;                                            \
        const unsigned short* srcA = Ab + (size_t)row * KK + k0_ + sgrp * 8;      \
        __builtin_amdgcn_global_load_lds(                                         \
            (const __attribute__((address_space(1))) void*)srcA,                  \
            (__attribute__((address_space(3))) void*)&As[BUF][inst * 512], 16, 0, 0); \
    }                                                                             \
    _Pragma("unroll")                                                             \
    for (int ii = 0; ii < 2; ++ii) {                                              \
        const int inst = wave * 2 + ii;                                           \
        const int row = inst * 8 + l8;                                            \
        int prow = p0 + row;                                                      \
        prow = prow < NP ? prow : NP - 1;                                         \
        const unsigned short* srcB = Bb + (size_t)prow * KK + k0_ + sgrp * 8;     \
        __builtin_amdgcn_global_load_lds(                                         \
            (const __attribute__((address_space(1))) void*)srcB,                  \
            (__attribute__((address_space(3))) void*)&Bs[BUF][inst * 512], 16, 0, 0); \
    }                                                                             \
} while (0)

#define COMPUTE(BUF) do {                                                         \
    _Pragma("unroll")                                                             \
    for (int kk = 0; kk < 2; ++kk) {                                              \
        short8 a[4], bfr[2];                                                      \
        const int g8 = (((kk * 4) + (lane >> 4)) ^ (lane & 7)) << 3;              \
        const int rA = wr * 64 + (lane & 15);                                     \
        const int rB = wc * 32 + (lane & 15);                                     \
        _Pragma("unroll")                                                         \
        for (int m = 0; m < 4; ++m)                                               \
            a[m] = *(const short8*)&As[BUF][(rA + m * 16) * 64 + g8];             \
        _Pragma("unroll")                                                         \
        for (int n = 0; n < 2; ++n)                                               \
            bfr[n] = *(const short8*)&Bs[BUF][(rB + n * 16) * 64 + g8];           \
        _Pragma("unroll")                                                         \
        for (int m = 0; m < 4; ++m)                                               \
            _Pragma("unroll")                                                     \
            for (int n = 0; n < 2; ++n)                                           \
                acc[m][n] = __builtin_amdgcn_mfma_f32_16x16x32_bf16(              \
                    a[m], bfr[n], acc[m][n], 0, 0, 0);                            \
    }                                                                             \
} while (0)

    STAGE(0, 0);
    __syncthreads();

    int cur = 0;
#pragma unroll 1
    for (int kt = 0; kt < 35; ++kt) {
        STAGE(cur ^ 1, kt + 1);      // next-tile loads fly under this tile's MFMA
        COMPUTE(cur);
        __syncthreads();             // drains vmcnt(0)+lgkmcnt(0)
        cur ^= 1;
    }
    COMPUTE(cur);

#undef STAGE
#undef COMPUTE

    float* ob = out + ((size_t)mimg * OCH + g * OUTG) * NP;
    const int o0 = m0 + wr * 64 + ((lane >> 4) << 2);
    const int pc = p0 + wc * 32 + (lane & 15);
#pragma unroll
    for (int n = 0; n < 2; ++n) {
        int p = pc + n * 16;
        if (p >= NP) continue;
#pragma unroll
        for (int m = 0; m < 4; ++m) {
#pragma unroll
            for (int r = 0; r < 4; ++r)
                ob[(size_t)(o0 + m * 16 + r) * NP + p] = acc[m][n][r];
        }
    }
}

extern "C" void kernel_launch(void* const* d_in, const int* in_sizes, int n_in,
                              void* d_out, int out_size, void* d_ws, size_t ws_size,
                              hipStream_t stream) {
    const float* x   = (const float*)d_in[0];
    const float* tf  = (const float*)d_in[1];
    const float* off = (const float*)d_in[2];
    float* out = (float*)d_out;

    unsigned short* xt  = (unsigned short*)d_ws;                    // [16][1296][2304] bf16
    unsigned short* wbf = xt + (size_t)NB * NP * KK;                // [1024][2304] bf16

    hipLaunchKernelGGL(cvt_filter, dim3(OCH), dim3(256), 0, stream, tf, wbf);
    hipLaunchKernelGGL(sample_kernel, dim3(NB * HH * 2), dim3(256), 0, stream, x, off, xt);
    hipLaunchKernelGGL(gemm_kernel, dim3(672), dim3(256), 0, stream, wbf, xt, out);
}

// Round 8
// 72.449 us; speedup vs baseline: 1.7871x; 1.0201x over previous
//
#include <hip/hip_runtime.h>
#include <hip/hip_bf16.h>

// DeformConv2d: x[4,4,256,36,36] f32, filter[1024,256,3,3] f32, offset[16,2] f32
// out[4,1024,36,36] f32.
// R8 = R7 + counted-vmcnt GEMM pipeline (T4): never drain vmcnt to 0 in the main
// loop; raw s_barrier pair per iter. STAGE(kt+1) flies under COMPUTE(kt) and has
// a full iteration to land. K layout k' = n*256+c. ws = 100,270,080 B.

#define HH 36
#define WW 36
#define CT 256
#define NB 16
#define KK 2304      // 9*256
#define NP 1296      // 36*36
#define OCH 1024
#define OUTG 256

typedef __attribute__((ext_vector_type(8))) short short8;
typedef __attribute__((ext_vector_type(4))) float f32x4;
typedef __attribute__((ext_vector_type(4))) unsigned short us4;
typedef __attribute__((ext_vector_type(4))) unsigned uint4v;

__device__ __forceinline__ unsigned short f2bf(float v) {
    unsigned u = __float_as_uint(v);
    u += 0x7fffu + ((u >> 16) & 1u);   // RNE
    return (unsigned short)(u >> 16);
}
__device__ __forceinline__ unsigned pk2bf(float lo, float hi) {
    __hip_bfloat162 h = __float22bfloat162_rn(float2{lo, hi});   // v_cvt_pk_bf16_f32
    return *reinterpret_cast<unsigned*>(&h);
}

// ---------------- kernel 1: filter fp32 [o][c*9+n] -> bf16 [o][n*256+c] ----------
__global__ __launch_bounds__(256) void cvt_filter(const float* __restrict__ f,
                                                  unsigned short* __restrict__ w) {
    const int o = blockIdx.x;
    const float* fo = f + (size_t)o * KK;
    unsigned short* wo = w + (size_t)o * KK;
    for (int k4 = threadIdx.x * 4; k4 < KK; k4 += 1024) {
        int n = k4 >> 8;          // tap
        int c = k4 & 255;         // channel (multiple of 4)
        us4 v;
#pragma unroll
        for (int cc = 0; cc < 4; ++cc) v[cc] = f2bf(fo[(c + cc) * 9 + n]);
        *reinterpret_cast<us4*>(wo + k4) = v;
    }
}

// ---------------- kernel 2: deformable bilinear sampling -> Xoff^T bf16 -----------
// grid 1152 = 16b * 36y * 2 half(128ch), XCD-swizzled (2 b per XCD, matches gemm).
__global__ __launch_bounds__(256) void sample_kernel(const float* __restrict__ x,
                                                     const float* __restrict__ off,
                                                     unsigned short* __restrict__ xt) {
    const int wid = (blockIdx.x & 7) * 144 + (blockIdx.x >> 3);
    const int b = wid / 72;
    const int rem = wid - b * 72;
    const int y = rem >> 1;
    const int half = rem & 1;
    const int tid = threadIdx.x;
    const float sx = 3.0f / off[2 * b + 0];
    const float sy = 3.0f / off[2 * b + 1];

    // row (i) tables: per-thread registers (block-uniform)
    int qxl[3], qxr[3]; float gxl[3], gxr[3];
    bool lok[3], rok[3];
#pragma unroll
    for (int i = 0; i < 3; ++i) {
        float px = (float)(y + 1) + (float)(i - 1) * sx;
        float pc = fminf(fmaxf(px, 0.f), 37.f);
        float fl = floorf(px);
        float ql = fminf(fmaxf(fl, 0.f), 37.f);
        float qr = fminf(fmaxf(fl + 1.f, 0.f), 37.f);
        qxl[i] = (int)ql; qxr[i] = (int)qr;
        gxl[i] = 1.f + (ql - pc);
        gxr[i] = 1.f - (qr - pc);
        lok[i] = (qxl[i] >= 1 && qxl[i] <= 36);
        rok[i] = (qxr[i] >= 1 && qxr[i] <= 36);
    }

    // column (x,j) tables in LDS
    __shared__ int   s_qyl[HH * 3], s_qyr[HH * 3];
    __shared__ float s_gyl[HH * 3], s_gyr[HH * 3];
    if (tid < HH * 3) {
        int xx = tid / 3, j = tid % 3;
        float py = (float)(xx + 1) + (float)(j - 1) * sy;
        float pc = fminf(fmaxf(py, 0.f), 37.f);
        float fl = floorf(py);
        float ql = fminf(fmaxf(fl, 0.f), 37.f);
        float qr = fminf(fmaxf(fl + 1.f, 0.f), 37.f);
        s_qyl[tid] = (int)ql; s_qyr[tid] = (int)qr;
        s_gyl[tid] = 1.f + (ql - pc);
        s_gyr[tid] = 1.f - (qr - pc);
    }

    // row-lerped tile, c-contiguous: xr[i][col 0..37][c 0..63] f32 (29.2 KB)
    __shared__ float xr[3 * 38 * 64];

    for (int chunk = 0; chunk < 2; ++chunk) {
        const int c0 = half * 128 + chunk * 64;
        __syncthreads();      // xr reusable (prev phase-2 done); covers tables iter0

        // boundary cols 0 and 37 are zero (zero padding)
        for (int t = tid; t < 384; t += 256) {
            int i = t / 128, r3 = t & 127;
            int col = (r3 & 64) ? 37 : 0, c = r3 & 63;
            xr[(i * 38 + col) * 64 + c] = 0.f;
        }

        // phase 1: row-lerp. tasks (i, c, colquad): coalesced float4 col-reads,
        // 4 scalar LDS writes (stride 256B) per task.
        const float* xb = x + (size_t)(b * CT + c0) * NP;
        for (int t = tid; t < 3 * 64 * 9; t += 256) {
            const int i = t / 576;
            const int r2 = t - i * 576;
            const int c = r2 / 9;
            const int cq = r2 - c * 9;
            const int colb = 1 + cq * 4;          // padded col of elem 0
            const float* xc = xb + c * NP;
            float4 vl = make_float4(0.f, 0.f, 0.f, 0.f);
            float4 vr = vl;
            if (lok[i]) vl = *(const float4*)(xc + (qxl[i] - 1) * WW + colb - 1);
            if (rok[i]) vr = *(const float4*)(xc + (qxr[i] - 1) * WW + colb - 1);
            float* dst = &xr[(i * 38 + colb) * 64 + c];
            dst[0]   = gxl[i] * vl.x + gxr[i] * vr.x;
            dst[64]  = gxl[i] * vl.y + gxr[i] * vr.y;
            dst[128] = gxl[i] * vl.z + gxr[i] * vr.z;
            dst[192] = gxl[i] * vl.w + gxr[i] * vr.w;
        }
        __syncthreads();

        // phase 2: column-lerp + pack. tasks (xi, c8): 9 taps x 8 channels each.
        for (int t = tid; t < 36 * 8; t += 256) {
            const int xi = t >> 3;
            const int c8 = t & 7;
            unsigned short* op = xt + ((size_t)b * NP + y * WW + xi) * KK + c0 + c8 * 8;
#pragma unroll
            for (int n = 0; n < 9; ++n) {
                const int i = n / 3, j = n - i * 3;
                const int tq = xi * 3 + j;
                const float gl = s_gyl[tq], gr = s_gyr[tq];
                const float* L = &xr[(i * 38 + s_qyl[tq]) * 64 + c8 * 8];
                const float* R = &xr[(i * 38 + s_qyr[tq]) * 64 + c8 * 8];
                f32x4 L0 = *(const f32x4*)L, L1 = *(const f32x4*)(L + 4);
                f32x4 R0 = *(const f32x4*)R, R1 = *(const f32x4*)(R + 4);
                uint4v w;
                w[0] = pk2bf(gl * L0[0] + gr * R0[0], gl * L0[1] + gr * R0[1]);
                w[1] = pk2bf(gl * L0[2] + gr * R0[2], gl * L0[3] + gr * R0[3]);
                w[2] = pk2bf(gl * L1[0] + gr * R1[0], gl * L1[1] + gr * R1[1]);
                w[3] = pk2bf(gl * L1[2] + gr * R1[2], gl * L1[3] + gr * R1[3]);
                *reinterpret_cast<uint4v*>(op + n * 256) = w;
            }
        }
    }
}

// ---------------- kernel 3: MFMA GEMM, 128x64, dbuf, counted-vmcnt pipeline -------
__global__ __launch_bounds__(256) void gemm_kernel(const unsigned short* __restrict__ wbf,
                                                   const unsigned short* __restrict__ xt,
                                                   float* __restrict__ out) {
    // 672 blocks = 8 XCD * 84; 84 per XCD = 2 b's worth (42 tiles per b)
    const int wid = (blockIdx.x & 7) * 84 + (blockIdx.x >> 3);
    const int b = wid / 42;
    const int rem = wid - b * 42;
    const int mt = rem / 21;
    const int nt = rem - mt * 21;
    const int m0 = mt * 128;
    const int p0 = nt * 64;
    const int g = b & 3;
    const int mimg = b >> 2;

    const unsigned short* Ab = wbf + (size_t)(g * OUTG + m0) * KK;
    const unsigned short* Bb = xt + (size_t)b * NP * KK;

    __shared__ __align__(16) unsigned short As[2][128 * 64];
    __shared__ __align__(16) unsigned short Bs[2][64 * 64];

    const int tid = threadIdx.x;
    const int wave = tid >> 6, lane = tid & 63;
    const int wr = wave >> 1, wc = wave & 1;
    const int l8 = lane >> 3;
    const int sgrp = (lane & 7) ^ l8;         // pre-swizzled source column group

    f32x4 acc[4][2] = {};

#define STAGE(BUF, KT) do {                                                       \
    const int k0_ = (KT) * 64;                                                    \
    _Pragma("unroll")                                                             \
    for (int ii = 0; ii < 4; ++ii) {                                              \
        const int inst = wave * 4 + ii;                                           \
        const int row = inst * 8 + l8;                                            \
        const unsigned short* srcA = Ab + (size_t)row * KK + k0_ + sgrp * 8;      \
        __builtin_amdgcn_global_load_lds(                                         \
            (const __attribute__((address_space(1))) void*)srcA,                  \
            (__attribute__((address_space(3))) void*)&As[BUF][inst * 512], 16, 0, 0); \
    }                                                                             \
    _Pragma("unroll")                                                             \
    for (int ii = 0; ii < 2; ++ii) {                                              \
        const int inst = wave * 2 + ii;                                           \
        const int row = inst * 8 + l8;                                            \
        int prow = p0 + row;                                                      \
        prow = prow < NP ? prow : NP - 1;                                         \
        const unsigned short* srcB = Bb + (size_t)prow * KK + k0_ + sgrp * 8;     \
        __builtin_amdgcn_global_load_lds(                                         \
            (const __attribute__((address_space(1))) void*)srcB,                  \
            (__attribute__((address_space(3))) void*)&Bs[BUF][inst * 512], 16, 0, 0); \
    }                                                                             \
} while (0)

#define COMPUTE(BUF) do {                                                         \
    _Pragma("unroll")                                                             \
    for (int kk = 0; kk < 2; ++kk) {                                              \
        short8 a[4], bfr[2];                                                      \
        const int g8 = (((kk * 4) + (lane >> 4)) ^ (lane & 7)) << 3;              \
        const int rA = wr * 64 + (lane & 15);                                     \
        const int rB = wc * 32 + (lane & 15);                                     \
        _Pragma("unroll")                                                         \
        for (int m = 0; m < 4; ++m)                                               \
            a[m] = *(const short8*)&As[BUF][(rA + m * 16) * 64 + g8];             \
        _Pragma("unroll")                                                         \
        for (int n = 0; n < 2; ++n)                                               \
            bfr[n] = *(const short8*)&Bs[BUF][(rB + n * 16) * 64 + g8];           \
        _Pragma("unroll")                                                         \
        for (int m = 0; m < 4; ++m)                                               \
            _Pragma("unroll")                                                     \
            for (int n = 0; n < 2; ++n)                                           \
                acc[m][n] = __builtin_amdgcn_mfma_f32_16x16x32_bf16(              \
                    a[m], bfr[n], acc[m][n], 0, 0, 0);                            \
    }                                                                             \
} while (0)

    STAGE(0, 0);                         // 6 loads in flight

#pragma unroll 1
    for (int kt = 0; kt < 35; ++kt) {
        STAGE((kt + 1) & 1, kt + 1);     // +6 loads -> 12 in flight
        // wait ONLY for tile kt's 6 loads; kt+1's stay in flight across barrier
        asm volatile("s_waitcnt vmcnt(6)" ::: "memory");
        __builtin_amdgcn_sched_barrier(0);
        __builtin_amdgcn_s_barrier();    // all waves' tile-kt loads landed
        COMPUTE(kt & 1);
        __builtin_amdgcn_s_barrier();    // readers done before next STAGE overwrites
    }
    asm volatile("s_waitcnt vmcnt(0)" ::: "memory");
    __builtin_amdgcn_sched_barrier(0);
    __builtin_amdgcn_s_barrier();
    COMPUTE(35 & 1);

#undef STAGE
#undef COMPUTE

    float* ob = out + ((size_t)mimg * OCH + g * OUTG) * NP;
    const int o0 = m0 + wr * 64 + ((lane >> 4) << 2);
    const int pc = p0 + wc * 32 + (lane & 15);
#pragma unroll
    for (int n = 0; n < 2; ++n) {
        int p = pc + n * 16;
        if (p >= NP) continue;
#pragma unroll
        for (int m = 0; m < 4; ++m) {
#pragma unroll
            for (int r = 0; r < 4; ++r)
                ob[(size_t)(o0 + m * 16 + r) * NP + p] = acc[m][n][r];
        }
    }
}

extern "C" void kernel_launch(void* const* d_in, const int* in_sizes, int n_in,
                              void* d_out, int out_size, void* d_ws, size_t ws_size,
                              hipStream_t stream) {
    const float* x   = (const float*)d_in[0];
    const float* tf  = (const float*)d_in[1];
    const float* off = (const float*)d_in[2];
    float* out = (float*)d_out;

    unsigned short* xt  = (unsigned short*)d_ws;                    // [16][1296][2304] bf16
    unsigned short* wbf = xt + (size_t)NB * NP * KK;                // [1024][2304] bf16

    hipLaunchKernelGGL(cvt_filter, dim3(OCH), dim3(256), 0, stream, tf, wbf);
    hipLaunchKernelGGL(sample_kernel, dim3(NB * HH * 2), dim3(256), 0, stream, x, off, xt);
    hipLaunchKernelGGL(gemm_kernel, dim3(672), dim3(256), 0, stream, wbf, xt, out);
}